// Round 1
// baseline (407.820 us; speedup 1.0000x reference)
//
#include <hip/hip_runtime.h>

#define LN_EPS 1e-5f

typedef __attribute__((ext_vector_type(8))) short bf16x8;
typedef __attribute__((ext_vector_type(4))) float f32x4;

__device__ __forceinline__ unsigned short f2bf(float f){
  unsigned u = __builtin_bit_cast(unsigned, f);
  u = (u + 0x7fffu + ((u >> 16) & 1u)) >> 16;
  return (unsigned short)u;
}

// ---------------------------------------------------------------------------
// Kernel 0: WqT[n][d] = bf16(Wq[d][n])
// ---------------------------------------------------------------------------
__global__ void k_wqt(const float* __restrict__ Wq, unsigned short* __restrict__ WqT){
  const int tid = blockIdx.x * 256 + threadIdx.x;      // 512*512 threads
  const int d = tid >> 9, n = tid & 511;
  WqT[(size_t)n * 512 + d] = f2bf(Wq[(size_t)d * 512 + n]);
}

// ---------------------------------------------------------------------------
// Kernel 1: cond LN + K/V projection.
// grid (4 dout-chunks, 5 n-chunks, 24 bc), 256 threads
// dc 0,1 -> k douts dc*256..; dc 2,3 -> v douts (dc-2)*256..
// ---------------------------------------------------------------------------
__global__ void k_condkv(const float* __restrict__ cond, const int* __restrict__ idx,
                         const float* __restrict__ tg, const float* __restrict__ tb,
                         const float* __restrict__ Wk, const float* __restrict__ bk,
                         const float* __restrict__ Wv, const float* __restrict__ bv,
                         float* __restrict__ kbuf, float* __restrict__ vbuf)
{
  __shared__ float cn[16][768];
  const int bc = blockIdx.z, nc = blockIdx.y, dc = blockIdx.x;
  const int b = idx[bc];
  const int n0 = nc * 16;
  int nrows = 77 - n0; if(nrows > 16) nrows = 16;
  const int w = threadIdx.x >> 6, lane = threadIdx.x & 63;

  for(int r = w; r < nrows; r += 4){
    const float* src = cond + ((size_t)b * 77 + n0 + r) * 768;
    float vals[12]; float s1 = 0.f, s2 = 0.f;
    #pragma unroll
    for(int i=0;i<12;i++){ float x = src[lane + i*64]; vals[i]=x; s1+=x; s2+=x*x; }
    #pragma unroll
    for(int off=1; off<64; off<<=1){ s1 += __shfl_xor(s1, off); s2 += __shfl_xor(s2, off); }
    const float mu  = s1 * (1.f/768.f);
    const float var = s2 * (1.f/768.f) - mu*mu;
    const float rs  = rsqrtf(var + LN_EPS);
    #pragma unroll
    for(int i=0;i<12;i++){ const int c2 = lane + i*64; cn[r][c2] = (vals[i]-mu)*rs*tg[c2] + tb[c2]; }
  }
  __syncthreads();

  const int dq = threadIdx.x & 63;
  const int part = threadIdx.x >> 6;
  const float* W    = (dc < 2) ? Wk : Wv;
  const float* bias = (dc < 2) ? bk : bv;
  float* obuf       = (dc < 2) ? kbuf : vbuf;
  const int d0 = (dc & 1) * 256 + dq * 4;

  float acc[4][4] = {};
  for(int i=0;i<768;i++){
    const float4 wv = *(const float4*)(W + (size_t)i * 512 + d0);
    #pragma unroll
    for(int j=0;j<4;j++){
      const float c = cn[part*4 + j][i];
      acc[j][0] += c * wv.x; acc[j][1] += c * wv.y;
      acc[j][2] += c * wv.z; acc[j][3] += c * wv.w;
    }
  }
  #pragma unroll
  for(int j=0;j<4;j++){
    const int r = part*4 + j, n = n0 + r;
    if(r < nrows){
      float4 o;
      o.x = acc[j][0] + bias[d0+0];
      o.y = acc[j][1] + bias[d0+1];
      o.z = acc[j][2] + bias[d0+2];
      o.w = acc[j][3] + bias[d0+3];
      *(float4*)(obuf + ((size_t)bc * 77 + n) * 512 + d0) = o;
    }
  }
}

// ---------------------------------------------------------------------------
// Kernel 2: per (h, bc): softmax K over tokens, ctxT[v][k] = sum_n softK[n][k]*V[n][v]
// ---------------------------------------------------------------------------
__global__ void k_ctx(const float* __restrict__ kbuf, const float* __restrict__ vbuf,
                      unsigned short* __restrict__ ctxT)
{
  __shared__ float kk[77][64];
  __shared__ float vv[77][64];
  __shared__ float inv_s[64];
  const int h = blockIdx.x, bc = blockIdx.y;
  const int tid = threadIdx.x;
  for(int e = tid; e < 77*64; e += 256){
    const int n = e >> 6, c = e & 63;
    kk[n][c] = kbuf[((size_t)bc * 77 + n) * 512 + h*64 + c];
    vv[n][c] = vbuf[((size_t)bc * 77 + n) * 512 + h*64 + c];
  }
  __syncthreads();
  if(tid < 64){
    float m = -1e30f;
    for(int n=0;n<77;n++) m = fmaxf(m, kk[n][tid]);
    float s = 0.f;
    for(int n=0;n<77;n++){ const float e = __expf(kk[n][tid] - m); kk[n][tid] = e; s += e; }
    inv_s[tid] = 1.f / s;
  }
  __syncthreads();
  #pragma unroll
  for(int j=0;j<16;j++){
    const int o = tid + 256*j;
    const int v = o >> 6, k2 = o & 63;
    float a = 0.f;
    for(int n=0;n<77;n++) a += kk[n][k2] * vv[n][v];
    ctxT[((size_t)(bc*8 + h)) * 4096 + v*64 + k2] = f2bf(a * inv_s[k2]);
  }
}

// ---------------------------------------------------------------------------
// Kernel 3: copy non-conditioned batches
// ---------------------------------------------------------------------------
__global__ void k_copy(const float* __restrict__ in, const int* __restrict__ idx,
                       float* __restrict__ out)
{
  const int b = blockIdx.y;
  bool member = false;
  for(int i=0;i<24;i++) member |= (idx[i] == b);
  if(member) return;
  const float4* s = (const float4*)(in  + (size_t)b * 512 * 4096);
  float4*       d = (float4*)      (out + (size_t)b * 512 * 4096);
  for(int i = blockIdx.x*256 + threadIdx.x; i < 512*4096/4; i += 128*256) d[i] = s[i];
}

// ---------------------------------------------------------------------------
// Kernel 4: main fused kernel. grid (128 t-tiles, 24 bc), 256 threads (4 waves).
// Block: 32 t's x 512 douts. Wave w owns douts [w*128, w*128+128) = heads 2w,2w+1.
// ---------------------------------------------------------------------------
__global__ __launch_bounds__(256, 2)
void k_main(const float* __restrict__ input, const int* __restrict__ idx,
            const float* __restrict__ ln_g, const float* __restrict__ ln_b,
            const unsigned short* __restrict__ WqT, const float* __restrict__ bq,
            const unsigned short* __restrict__ ctxT, float* __restrict__ out)
{
  __shared__ __align__(16) unsigned short A[32][40];     // LN'd x tile, [t][k-local]
  __shared__ __align__(16) unsigned short Bt[512][40];   // WqT slice, [n][k-local]
  __shared__ __align__(16) unsigned short P[4][32][136]; // per wave softmaxed q [t][k(128)]
  __shared__ float mu_s[32], rs_s[32];
  __shared__ float red1[4][8][4], red2[4][8][4];

  const int tid  = threadIdx.x;
  const int lane = tid & 63;
  const int w    = tid >> 6;
  const int col  = lane & 15;
  const int g    = lane >> 4;
  const int bc   = blockIdx.y;
  const int b    = idx[bc];
  const int t0   = blockIdx.x * 32;
  const float* xb = input + (size_t)b * (512*4096);
  float*       ob = out   + (size_t)b * (512*4096);

  // ---- LN stats per t (mean/rstd over d=512) ----
  {
    const int p  = tid & 7;   // t-quad: t = 4p..4p+3
    const int dg = tid >> 3;  // d rows dg, dg+32, ...
    float s1[4] = {0,0,0,0}, s2[4] = {0,0,0,0};
    for(int i=0;i<16;i++){
      const float4 x = *(const float4*)(xb + (size_t)(dg + i*32) * 4096 + t0 + p*4);
      s1[0]+=x.x; s1[1]+=x.y; s1[2]+=x.z; s1[3]+=x.w;
      s2[0]+=x.x*x.x; s2[1]+=x.y*x.y; s2[2]+=x.z*x.z; s2[3]+=x.w*x.w;
    }
    #pragma unroll
    for(int off=8; off<64; off<<=1){
      #pragma unroll
      for(int j=0;j<4;j++){ s1[j] += __shfl_xor(s1[j], off); s2[j] += __shfl_xor(s2[j], off); }
    }
    if(lane < 8){
      #pragma unroll
      for(int j=0;j<4;j++){ red1[w][lane][j] = s1[j]; red2[w][lane][j] = s2[j]; }
    }
    __syncthreads();
    if(tid < 32){
      const int pp = tid >> 2, j = tid & 3;
      float a = 0.f, c = 0.f;
      #pragma unroll
      for(int ww=0; ww<4; ++ww){ a += red1[ww][pp][j]; c += red2[ww][pp][j]; }
      const float mu  = a * (1.f/512.f);
      const float var = c * (1.f/512.f) - mu*mu;
      mu_s[tid] = mu;
      rs_s[tid] = rsqrtf(var + LN_EPS);
    }
    __syncthreads();
  }

  f32x4 acc[2][8] = {};

  // ---- K loop: q = LN(x) @ Wq ----
  for(int ks=0; ks<16; ++ks){
    const int dbase = ks * 32;
    // build A tile (apply LN, cast bf16, transpose into [t][d])
    {
      const int dl = tid >> 3;
      const int p  = tid & 7;
      const int d  = dbase + dl;
      const float4 x = *(const float4*)(xb + (size_t)d * 4096 + t0 + p*4);
      const float gv = ln_g[d], bv = ln_b[d];
      const int t = p * 4;
      A[t+0][dl] = f2bf((x.x - mu_s[t+0]) * rs_s[t+0] * gv + bv);
      A[t+1][dl] = f2bf((x.y - mu_s[t+1]) * rs_s[t+1] * gv + bv);
      A[t+2][dl] = f2bf((x.z - mu_s[t+2]) * rs_s[t+2] * gv + bv);
      A[t+3][dl] = f2bf((x.w - mu_s[t+3]) * rs_s[t+3] * gv + bv);
    }
    // load B tile: Bt[n][0..31] = WqT[n][dbase..dbase+31]
    #pragma unroll
    for(int i=0;i<8;i++){
      const int c  = tid + i*256;
      const int n  = c >> 2;
      const int o8 = (c & 3) * 8;
      *(int4*)(&Bt[n][o8]) = *(const int4*)(WqT + (size_t)n * 512 + dbase + o8);
    }
    __syncthreads();
    const bf16x8 af0 = *(const bf16x8*)(&A[col     ][g*8]);
    const bf16x8 af1 = *(const bf16x8*)(&A[col + 16][g*8]);
    #pragma unroll
    for(int nt=0; nt<8; ++nt){
      const bf16x8 bf = *(const bf16x8*)(&Bt[w*128 + nt*16 + col][g*8]);
      acc[0][nt] = __builtin_amdgcn_mfma_f32_16x16x32_bf16(af0, bf, acc[0][nt], 0, 0, 0);
      acc[1][nt] = __builtin_amdgcn_mfma_f32_16x16x32_bf16(af1, bf, acc[1][nt], 0, 0, 0);
    }
    __syncthreads();
  }

  // ---- bias + per-head feature softmax (over 64 douts), in place ----
  #pragma unroll
  for(int mt=0; mt<2; ++mt){
    #pragma unroll
    for(int hh=0; hh<2; ++hh){
      #pragma unroll
      for(int q=0; q<4; ++q){
        const int nt = hh*4 + q;
        const float bqv = bq[w*128 + nt*16 + col];
        #pragma unroll
        for(int r=0;r<4;++r) acc[mt][nt][r] += bqv;
      }
      #pragma unroll
      for(int r=0;r<4;++r){
        float m = acc[mt][hh*4+0][r];
        #pragma unroll
        for(int q=1;q<4;++q) m = fmaxf(m, acc[mt][hh*4+q][r]);
        m = fmaxf(m, __shfl_xor(m, 1));
        m = fmaxf(m, __shfl_xor(m, 2));
        m = fmaxf(m, __shfl_xor(m, 4));
        m = fmaxf(m, __shfl_xor(m, 8));
        float s = 0.f;
        #pragma unroll
        for(int q=0;q<4;++q){
          const float e = __expf(acc[mt][hh*4+q][r] - m);
          acc[mt][hh*4+q][r] = e;
          s += e;
        }
        s += __shfl_xor(s, 1);
        s += __shfl_xor(s, 2);
        s += __shfl_xor(s, 4);
        s += __shfl_xor(s, 8);
        const float inv = 1.f / s;
        #pragma unroll
        for(int q=0;q<4;++q) acc[mt][hh*4+q][r] *= inv;
      }
    }
  }

  // store P (wave-private region, no barrier needed)
  #pragma unroll
  for(int mt=0; mt<2; ++mt)
    #pragma unroll
    for(int nt=0; nt<8; ++nt)
      #pragma unroll
      for(int r=0; r<4; ++r)
        P[w][mt*16 + g*4 + r][nt*16 + col] = f2bf(acc[mt][nt][r]);

  // ---- PV (D[v][t] = ctxT[v][:] . P[t][:]) + residual + store ----
  #pragma unroll
  for(int hh=0; hh<2; ++hh){
    const int head = w*2 + hh;
    const unsigned short* cb = ctxT + ((size_t)(bc*8 + head)) * 4096;
    f32x4 y[4][2] = {};
    #pragma unroll
    for(int ks2=0; ks2<2; ++ks2){
      const bf16x8 pb0 = *(const bf16x8*)(&P[w][col     ][hh*64 + ks2*32 + g*8]);
      const bf16x8 pb1 = *(const bf16x8*)(&P[w][col + 16][hh*64 + ks2*32 + g*8]);
      #pragma unroll
      for(int vt=0; vt<4; ++vt){
        const bf16x8 af = *(const bf16x8*)(cb + (size_t)(vt*16 + col) * 64 + ks2*32 + g*8);
        y[vt][0] = __builtin_amdgcn_mfma_f32_16x16x32_bf16(af, pb0, y[vt][0], 0, 0, 0);
        y[vt][1] = __builtin_amdgcn_mfma_f32_16x16x32_bf16(af, pb1, y[vt][1], 0, 0, 0);
      }
    }
    #pragma unroll
    for(int vt=0; vt<4; ++vt)
      #pragma unroll
      for(int tt=0; tt<2; ++tt)
        #pragma unroll
        for(int r=0; r<4; ++r){
          const size_t a = (size_t)(head*64 + vt*16 + g*4 + r) * 4096 + (size_t)(t0 + tt*16 + col);
          ob[a] = xb[a] + y[vt][tt][r];
        }
  }
}

// ---------------------------------------------------------------------------
extern "C" void kernel_launch(void* const* d_in, const int* in_sizes, int n_in,
                              void* d_out, int out_size, void* d_ws, size_t ws_size,
                              hipStream_t stream)
{
  const float* input = (const float*)d_in[0];
  const float* cond  = (const float*)d_in[1];
  const int*   idx   = (const int*)d_in[2];
  const float* ln_g  = (const float*)d_in[3];
  const float* ln_b  = (const float*)d_in[4];
  const float* tln_g = (const float*)d_in[5];
  const float* tln_b = (const float*)d_in[6];
  const float* Wq    = (const float*)d_in[7];
  const float* bq    = (const float*)d_in[8];
  const float* Wk    = (const float*)d_in[9];
  const float* bk    = (const float*)d_in[10];
  const float* Wv    = (const float*)d_in[11];
  const float* bv    = (const float*)d_in[12];
  float* out = (float*)d_out;
  char*  ws  = (char*)d_ws;

  unsigned short* WqT  = (unsigned short*)(ws);                       // 512 KB
  unsigned short* ctxT = (unsigned short*)(ws + 524288);              // 1.5 MB
  float* kbuf = (float*)(ws + 524288 + 1572864);                      // 3.61 MB
  float* vbuf = (float*)(ws + 524288 + 1572864 + 24*77*512*4);        // 3.61 MB

  k_wqt   <<<dim3(1024),    dim3(256), 0, stream>>>(Wq, WqT);
  k_condkv<<<dim3(4,5,24),  dim3(256), 0, stream>>>(cond, idx, tln_g, tln_b, Wk, bk, Wv, bv, kbuf, vbuf);
  k_ctx   <<<dim3(8,24),    dim3(256), 0, stream>>>(kbuf, vbuf, ctxT);
  k_copy  <<<dim3(128,32),  dim3(256), 0, stream>>>(input, idx, out);
  k_main  <<<dim3(128,24),  dim3(256), 0, stream>>>(input, idx, ln_g, ln_b, WqT, bq, ctxT, out);
}

// Round 2
// 406.511 us; speedup vs baseline: 1.0032x; 1.0032x over previous
//
#include <hip/hip_runtime.h>

#define LN_EPS 1e-5f

typedef __attribute__((ext_vector_type(8))) short bf16x8;
typedef __attribute__((ext_vector_type(8))) short s16x8;
typedef __attribute__((ext_vector_type(4))) float f32x4;

__device__ __forceinline__ unsigned short f2bf(float f){
  unsigned u = __builtin_bit_cast(unsigned, f);
  u = (u + 0x7fffu + ((u >> 16) & 1u)) >> 16;
  return (unsigned short)u;
}

__device__ __forceinline__ void gll16(const unsigned short* g, unsigned short* l){
  __builtin_amdgcn_global_load_lds(
      (const __attribute__((address_space(1))) unsigned int*)(g),
      (__attribute__((address_space(3))) unsigned int*)(l), 16, 0, 0);
}

// ---------------------------------------------------------------------------
// Kernel 0: WqT[n][d] = bf16(Wq[d][n])
// ---------------------------------------------------------------------------
__global__ void k_wqt(const float* __restrict__ Wq, unsigned short* __restrict__ WqT){
  const int tid = blockIdx.x * 256 + threadIdx.x;
  const int d = tid >> 9, n = tid & 511;
  WqT[(size_t)n * 512 + d] = f2bf(Wq[(size_t)d * 512 + n]);
}

// ---------------------------------------------------------------------------
// Kernel 1: cond LN + K/V projection (unchanged from R1, works)
// ---------------------------------------------------------------------------
__global__ void k_condkv(const float* __restrict__ cond, const int* __restrict__ idx,
                         const float* __restrict__ tg, const float* __restrict__ tb,
                         const float* __restrict__ Wk, const float* __restrict__ bk,
                         const float* __restrict__ Wv, const float* __restrict__ bv,
                         float* __restrict__ kbuf, float* __restrict__ vbuf)
{
  __shared__ float cn[16][768];
  const int bc = blockIdx.z, nc = blockIdx.y, dc = blockIdx.x;
  const int b = idx[bc];
  const int n0 = nc * 16;
  int nrows = 77 - n0; if(nrows > 16) nrows = 16;
  const int w = threadIdx.x >> 6, lane = threadIdx.x & 63;

  for(int r = w; r < nrows; r += 4){
    const float* src = cond + ((size_t)b * 77 + n0 + r) * 768;
    float vals[12]; float s1 = 0.f, s2 = 0.f;
    #pragma unroll
    for(int i=0;i<12;i++){ float x = src[lane + i*64]; vals[i]=x; s1+=x; s2+=x*x; }
    #pragma unroll
    for(int off=1; off<64; off<<=1){ s1 += __shfl_xor(s1, off); s2 += __shfl_xor(s2, off); }
    const float mu  = s1 * (1.f/768.f);
    const float var = s2 * (1.f/768.f) - mu*mu;
    const float rs  = rsqrtf(var + LN_EPS);
    #pragma unroll
    for(int i=0;i<12;i++){ const int c2 = lane + i*64; cn[r][c2] = (vals[i]-mu)*rs*tg[c2] + tb[c2]; }
  }
  __syncthreads();

  const int dq = threadIdx.x & 63;
  const int part = threadIdx.x >> 6;
  const float* W    = (dc < 2) ? Wk : Wv;
  const float* bias = (dc < 2) ? bk : bv;
  float* obuf       = (dc < 2) ? kbuf : vbuf;
  const int d0 = (dc & 1) * 256 + dq * 4;

  float acc[4][4] = {};
  for(int i=0;i<768;i++){
    const float4 wv = *(const float4*)(W + (size_t)i * 512 + d0);
    #pragma unroll
    for(int j=0;j<4;j++){
      const float c = cn[part*4 + j][i];
      acc[j][0] += c * wv.x; acc[j][1] += c * wv.y;
      acc[j][2] += c * wv.z; acc[j][3] += c * wv.w;
    }
  }
  #pragma unroll
  for(int j=0;j<4;j++){
    const int r = part*4 + j, n = n0 + r;
    if(r < nrows){
      float4 o;
      o.x = acc[j][0] + bias[d0+0];
      o.y = acc[j][1] + bias[d0+1];
      o.z = acc[j][2] + bias[d0+2];
      o.w = acc[j][3] + bias[d0+3];
      *(float4*)(obuf + ((size_t)bc * 77 + n) * 512 + d0) = o;
    }
  }
}

// ---------------------------------------------------------------------------
// Kernel 2: per (h, bc): softmax K over tokens, ctxT[v][k]
// ---------------------------------------------------------------------------
__global__ void k_ctx(const float* __restrict__ kbuf, const float* __restrict__ vbuf,
                      unsigned short* __restrict__ ctxT)
{
  __shared__ float kk[77][64];
  __shared__ float vv[77][64];
  __shared__ float inv_s[64];
  const int h = blockIdx.x, bc = blockIdx.y;
  const int tid = threadIdx.x;
  for(int e = tid; e < 77*64; e += 256){
    const int n = e >> 6, c = e & 63;
    kk[n][c] = kbuf[((size_t)bc * 77 + n) * 512 + h*64 + c];
    vv[n][c] = vbuf[((size_t)bc * 77 + n) * 512 + h*64 + c];
  }
  __syncthreads();
  if(tid < 64){
    float m = -1e30f;
    for(int n=0;n<77;n++) m = fmaxf(m, kk[n][tid]);
    float s = 0.f;
    for(int n=0;n<77;n++){ const float e = __expf(kk[n][tid] - m); kk[n][tid] = e; s += e; }
    inv_s[tid] = 1.f / s;
  }
  __syncthreads();
  #pragma unroll
  for(int j=0;j<16;j++){
    const int o = tid + 256*j;
    const int v = o >> 6, k2 = o & 63;
    float a = 0.f;
    for(int n=0;n<77;n++) a += kk[n][k2] * vv[n][v];
    ctxT[((size_t)(bc*8 + h)) * 4096 + v*64 + k2] = f2bf(a * inv_s[k2]);
  }
}

// ---------------------------------------------------------------------------
// Kernel 3: copy non-conditioned batches
// ---------------------------------------------------------------------------
__global__ void k_copy(const float* __restrict__ in, const int* __restrict__ idx,
                       float* __restrict__ out)
{
  const int b = blockIdx.y;
  bool member = false;
  for(int i=0;i<24;i++) member |= (idx[i] == b);
  if(member) return;
  const float4* s = (const float4*)(in  + (size_t)b * 512 * 4096);
  float4*       d = (float4*)      (out + (size_t)b * 512 * 4096);
  for(int i = blockIdx.x*256 + threadIdx.x; i < 512*4096/4; i += 128*256) d[i] = s[i];
}

// ---------------------------------------------------------------------------
// Kernel 5 (NEW): LN + transpose + bf16 cast.  xT[bc][t][d], bf16.
// grid (128 t-tiles, 24 bc), 256 threads.
// ---------------------------------------------------------------------------
__global__ __launch_bounds__(256, 2)
void k_lnt(const float* __restrict__ input, const int* __restrict__ idx,
           const float* __restrict__ ln_g, const float* __restrict__ ln_b,
           unsigned short* __restrict__ xT)
{
  __shared__ float buf[32][516];
  __shared__ float red1[32][8], red2[32][8];
  __shared__ float mu_s[32], rs_s[32];
  __shared__ float gbuf[512], bbuf[512];

  const int tid = threadIdx.x;
  const int bc = blockIdx.y;
  const int b  = idx[bc];
  const int t0 = blockIdx.x * 32;
  const float* xb = input + (size_t)b * (512*4096) + t0;

  // preload gamma/beta
  *(float2*)&gbuf[tid*2] = *(const float2*)&ln_g[tid*2];
  *(float2*)&bbuf[tid*2] = *(const float2*)&ln_b[tid*2];

  // load + transpose into LDS
  {
    const int p  = tid & 7;    // t-quad
    const int dg = tid >> 3;   // d-row group
    #pragma unroll
    for(int i=0;i<16;i++){
      const int d = dg + i*32;
      const float4 x = *(const float4*)(xb + (size_t)d * 4096 + p*4);
      buf[p*4+0][d] = x.x; buf[p*4+1][d] = x.y;
      buf[p*4+2][d] = x.z; buf[p*4+3][d] = x.w;
    }
  }
  __syncthreads();

  // stats: per t, 8 partial sums over contiguous 64-float chunks
  {
    const int t = tid & 31, part = tid >> 5;
    float s1 = 0.f, s2 = 0.f;
    #pragma unroll
    for(int i=0;i<16;i++){
      const float4 v = *(const float4*)&buf[t][part*64 + i*4];
      s1 += v.x+v.y+v.z+v.w;
      s2 += v.x*v.x + v.y*v.y + v.z*v.z + v.w*v.w;
    }
    red1[t][part] = s1; red2[t][part] = s2;
  }
  __syncthreads();
  if(tid < 32){
    float a = 0.f, c = 0.f;
    #pragma unroll
    for(int p=0;p<8;p++){ a += red1[tid][p]; c += red2[tid][p]; }
    const float mu  = a * (1.f/512.f);
    const float var = c * (1.f/512.f) - mu*mu;
    mu_s[tid] = mu; rs_s[tid] = rsqrtf(var + LN_EPS);
  }
  __syncthreads();

  // apply + cast + write coalesced rows of xT
  {
    const int c  = tid & 7;
    const int tt = tid >> 3;
    const float mu = mu_s[tt], rs = rs_s[tt];
    unsigned short* orow = xT + ((size_t)bc*4096 + t0 + tt) * 512;
    #pragma unroll
    for(int j=0;j<8;j++){
      const int d0 = c*8 + j*64;
      const float4 a  = *(const float4*)&buf[tt][d0];
      const float4 b4 = *(const float4*)&buf[tt][d0+4];
      const float4 g0 = *(const float4*)&gbuf[d0];
      const float4 g1 = *(const float4*)&gbuf[d0+4];
      const float4 h0 = *(const float4*)&bbuf[d0];
      const float4 h1 = *(const float4*)&bbuf[d0+4];
      s16x8 o;
      o[0] = (short)f2bf((a.x -mu)*rs*g0.x + h0.x);
      o[1] = (short)f2bf((a.y -mu)*rs*g0.y + h0.y);
      o[2] = (short)f2bf((a.z -mu)*rs*g0.z + h0.z);
      o[3] = (short)f2bf((a.w -mu)*rs*g0.w + h0.w);
      o[4] = (short)f2bf((b4.x-mu)*rs*g1.x + h1.x);
      o[5] = (short)f2bf((b4.y-mu)*rs*g1.y + h1.y);
      o[6] = (short)f2bf((b4.z-mu)*rs*g1.z + h1.z);
      o[7] = (short)f2bf((b4.w-mu)*rs*g1.w + h1.w);
      *(s16x8*)(orow + d0) = o;
    }
  }
}

// ---------------------------------------------------------------------------
// Kernel 6 (NEW): m97-style 128x128 GEMM (q = xT @ WqT^T) + fused
// softmax / PV / residual epilogue.
// grid (768 m-tiles, 4 n-tiles), 256 threads (4 waves, 2x2).
// Wave (wm, wn): rows t [wm*64,+64), cols dout [wn*64,+64) = one head.
// ---------------------------------------------------------------------------
__global__ __launch_bounds__(256, 2)
void k_gemm(const float* __restrict__ input, const int* __restrict__ idx,
            const unsigned short* __restrict__ xT, const unsigned short* __restrict__ WqT,
            const float* __restrict__ bq, const unsigned short* __restrict__ ctxT,
            float* __restrict__ out)
{
  __shared__ __align__(16) unsigned short As[128][32];
  __shared__ __align__(16) unsigned short Bs[128][32];
  __shared__ __align__(16) unsigned short P[4][64][72];

  const int tid  = threadIdx.x;
  const int lane = tid & 63;
  const int w    = tid >> 6;
  const int col  = lane & 15;
  const int g    = lane >> 4;
  const int wm   = w >> 1, wn = w & 1;
  const int mtile = blockIdx.x, ntile = blockIdx.y;
  const int bc   = mtile >> 5;
  const int tloc = (mtile & 31) * 128;
  const int b    = idx[bc];
  const size_t abase = (size_t)bc * 4096 + tloc;
  const int nbase = ntile * 128;

  const int fb0 = tid * 16;          // flat byte, issue 0
  const int fb1 = fb0 + 4096;        // issue 1
  const int r0 = fb0 >> 6, o0 = (fb0 & 63) >> 1;
  const int r1 = fb1 >> 6, o1 = (fb1 & 63) >> 1;
  unsigned short* Af = &As[0][0];
  unsigned short* Bf = &Bs[0][0];

  f32x4 acc[4][4] = {};

  for(int ks=0; ks<16; ++ks){
    const int dbase = ks * 32;
    __syncthreads();  // previous tile's reads complete
    gll16(xT  + (abase + r0) * 512 + dbase + o0, Af + (fb0 >> 1));
    gll16(xT  + (abase + r1) * 512 + dbase + o1, Af + (fb1 >> 1));
    gll16(WqT + (size_t)(nbase + r0) * 512 + dbase + o0, Bf + (fb0 >> 1));
    gll16(WqT + (size_t)(nbase + r1) * 512 + dbase + o1, Bf + (fb1 >> 1));
    __syncthreads();  // compiler drains vmcnt before barrier

    bf16x8 af[4], bfr[4];
    #pragma unroll
    for(int mt=0; mt<4; ++mt) af[mt]  = *(const bf16x8*)&As[wm*64 + mt*16 + col][g*8];
    #pragma unroll
    for(int nt=0; nt<4; ++nt) bfr[nt] = *(const bf16x8*)&Bs[wn*64 + nt*16 + col][g*8];
    #pragma unroll
    for(int mt=0; mt<4; ++mt)
      #pragma unroll
      for(int nt=0; nt<4; ++nt)
        acc[mt][nt] = __builtin_amdgcn_mfma_f32_16x16x32_bf16(af[mt], bfr[nt], acc[mt][nt], 0, 0, 0);
  }

  // ---- bias + per-head feature softmax (wave owns exactly one head) ----
  #pragma unroll
  for(int mt=0; mt<4; ++mt){
    #pragma unroll
    for(int nt=0; nt<4; ++nt){
      const float bqv = bq[nbase + wn*64 + nt*16 + col];
      #pragma unroll
      for(int r=0;r<4;++r) acc[mt][nt][r] += bqv;
    }
    #pragma unroll
    for(int r=0;r<4;++r){
      float m = acc[mt][0][r];
      #pragma unroll
      for(int q=1;q<4;++q) m = fmaxf(m, acc[mt][q][r]);
      m = fmaxf(m, __shfl_xor(m, 1));
      m = fmaxf(m, __shfl_xor(m, 2));
      m = fmaxf(m, __shfl_xor(m, 4));
      m = fmaxf(m, __shfl_xor(m, 8));
      float s = 0.f;
      #pragma unroll
      for(int q=0;q<4;++q){
        const float e = __expf(acc[mt][q][r] - m);
        acc[mt][q][r] = e; s += e;
      }
      s += __shfl_xor(s, 1);
      s += __shfl_xor(s, 2);
      s += __shfl_xor(s, 4);
      s += __shfl_xor(s, 8);
      const float inv = 1.f / s;
      #pragma unroll
      for(int q=0;q<4;++q) acc[mt][q][r] *= inv;
    }
  }

  // store P (wave-private region; same-wave DS ordering suffices)
  #pragma unroll
  for(int mt=0; mt<4; ++mt)
    #pragma unroll
    for(int nt=0; nt<4; ++nt)
      #pragma unroll
      for(int r=0; r<4; ++r)
        P[w][mt*16 + g*4 + r][nt*16 + col] = f2bf(acc[mt][nt][r]);

  // ---- PV: y[v][t] = ctxT[v][:] . P[t][:], + residual + store ----
  const int head = ntile*2 + wn;
  const unsigned short* cb = ctxT + ((size_t)(bc*8 + head)) * 4096;
  f32x4 y[4][4] = {};
  #pragma unroll
  for(int ks2=0; ks2<2; ++ks2){
    bf16x8 pb[4];
    #pragma unroll
    for(int tt=0; tt<4; ++tt) pb[tt] = *(const bf16x8*)&P[w][tt*16 + col][ks2*32 + g*8];
    #pragma unroll
    for(int vt=0; vt<4; ++vt){
      const bf16x8 av = *(const bf16x8*)(cb + (size_t)(vt*16 + col) * 64 + ks2*32 + g*8);
      #pragma unroll
      for(int tt=0; tt<4; ++tt)
        y[vt][tt] = __builtin_amdgcn_mfma_f32_16x16x32_bf16(av, pb[tt], y[vt][tt], 0, 0, 0);
    }
  }

  const float* xb = input + (size_t)b * (512*4096);
  float*       ob = out   + (size_t)b * (512*4096);
  #pragma unroll
  for(int vt=0; vt<4; ++vt)
    #pragma unroll
    for(int tt=0; tt<4; ++tt)
      #pragma unroll
      for(int r=0; r<4; ++r){
        const size_t a = (size_t)(head*64 + vt*16 + g*4 + r) * 4096
                       + (size_t)(tloc + wm*64 + tt*16 + col);
        ob[a] = xb[a] + y[vt][tt][r];
      }
}

// ---------------------------------------------------------------------------
// Kernel 4 (FALLBACK, R1 k_main) — used only if ws_size too small for xT
// ---------------------------------------------------------------------------
__global__ __launch_bounds__(256, 2)
void k_main(const float* __restrict__ input, const int* __restrict__ idx,
            const float* __restrict__ ln_g, const float* __restrict__ ln_b,
            const unsigned short* __restrict__ WqT, const float* __restrict__ bq,
            const unsigned short* __restrict__ ctxT, float* __restrict__ out)
{
  __shared__ __align__(16) unsigned short A[32][40];
  __shared__ __align__(16) unsigned short Bt[512][40];
  __shared__ __align__(16) unsigned short P[4][32][136];
  __shared__ float mu_s[32], rs_s[32];
  __shared__ float red1[4][8][4], red2[4][8][4];

  const int tid  = threadIdx.x;
  const int lane = tid & 63;
  const int w    = tid >> 6;
  const int col  = lane & 15;
  const int g    = lane >> 4;
  const int bc   = blockIdx.y;
  const int b    = idx[bc];
  const int t0   = blockIdx.x * 32;
  const float* xb = input + (size_t)b * (512*4096);
  float*       ob = out   + (size_t)b * (512*4096);

  {
    const int p  = tid & 7;
    const int dg = tid >> 3;
    float s1[4] = {0,0,0,0}, s2[4] = {0,0,0,0};
    for(int i=0;i<16;i++){
      const float4 x = *(const float4*)(xb + (size_t)(dg + i*32) * 4096 + t0 + p*4);
      s1[0]+=x.x; s1[1]+=x.y; s1[2]+=x.z; s1[3]+=x.w;
      s2[0]+=x.x*x.x; s2[1]+=x.y*x.y; s2[2]+=x.z*x.z; s2[3]+=x.w*x.w;
    }
    #pragma unroll
    for(int off=8; off<64; off<<=1){
      #pragma unroll
      for(int j=0;j<4;j++){ s1[j] += __shfl_xor(s1[j], off); s2[j] += __shfl_xor(s2[j], off); }
    }
    if(lane < 8){
      #pragma unroll
      for(int j=0;j<4;j++){ red1[w][lane][j] = s1[j]; red2[w][lane][j] = s2[j]; }
    }
    __syncthreads();
    if(tid < 32){
      const int pp = tid >> 2, j = tid & 3;
      float a = 0.f, c = 0.f;
      #pragma unroll
      for(int ww=0; ww<4; ++ww){ a += red1[ww][pp][j]; c += red2[ww][pp][j]; }
      const float mu  = a * (1.f/512.f);
      const float var = c * (1.f/512.f) - mu*mu;
      mu_s[tid] = mu;
      rs_s[tid] = rsqrtf(var + LN_EPS);
    }
    __syncthreads();
  }

  f32x4 acc[2][8] = {};

  for(int ks=0; ks<16; ++ks){
    const int dbase = ks * 32;
    {
      const int dl = tid >> 3;
      const int p  = tid & 7;
      const int d  = dbase + dl;
      const float4 x = *(const float4*)(xb + (size_t)d * 4096 + t0 + p*4);
      const float gv = ln_g[d], bv = ln_b[d];
      const int t = p * 4;
      A[t+0][dl] = f2bf((x.x - mu_s[t+0]) * rs_s[t+0] * gv + bv);
      A[t+1][dl] = f2bf((x.y - mu_s[t+1]) * rs_s[t+1] * gv + bv);
      A[t+2][dl] = f2bf((x.z - mu_s[t+2]) * rs_s[t+2] * gv + bv);
      A[t+3][dl] = f2bf((x.w - mu_s[t+3]) * rs_s[t+3] * gv + bv);
    }
    #pragma unroll
    for(int i=0;i<8;i++){
      const int c  = tid + i*256;
      const int n  = c >> 2;
      const int o8 = (c & 3) * 8;
      *(int4*)(&Bt[n][o8]) = *(const int4*)(WqT + (size_t)n * 512 + dbase + o8);
    }
    __syncthreads();
    const bf16x8 af0 = *(const bf16x8*)(&A[col     ][g*8]);
    const bf16x8 af1 = *(const bf16x8*)(&A[col + 16][g*8]);
    #pragma unroll
    for(int nt=0; nt<8; ++nt){
      const bf16x8 bf = *(const bf16x8*)(&Bt[w*128 + nt*16 + col][g*8]);
      acc[0][nt] = __builtin_amdgcn_mfma_f32_16x16x32_bf16(af0, bf, acc[0][nt], 0, 0, 0);
      acc[1][nt] = __builtin_amdgcn_mfma_f32_16x16x32_bf16(af1, bf, acc[1][nt], 0, 0, 0);
    }
    __syncthreads();
  }

  #pragma unroll
  for(int mt=0; mt<2; ++mt){
    #pragma unroll
    for(int hh=0; hh<2; ++hh){
      #pragma unroll
      for(int q=0; q<4; ++q){
        const int nt = hh*4 + q;
        const float bqv = bq[w*128 + nt*16 + col];
        #pragma unroll
        for(int r=0;r<4;++r) acc[mt][nt][r] += bqv;
      }
      #pragma unroll
      for(int r=0;r<4;++r){
        float m = acc[mt][hh*4+0][r];
        #pragma unroll
        for(int q=1;q<4;++q) m = fmaxf(m, acc[mt][hh*4+q][r]);
        m = fmaxf(m, __shfl_xor(m, 1));
        m = fmaxf(m, __shfl_xor(m, 2));
        m = fmaxf(m, __shfl_xor(m, 4));
        m = fmaxf(m, __shfl_xor(m, 8));
        float s = 0.f;
        #pragma unroll
        for(int q=0;q<4;++q){
          const float e = __expf(acc[mt][hh*4+q][r] - m);
          acc[mt][hh*4+q][r] = e;
          s += e;
        }
        s += __shfl_xor(s, 1);
        s += __shfl_xor(s, 2);
        s += __shfl_xor(s, 4);
        s += __shfl_xor(s, 8);
        const float inv = 1.f / s;
        #pragma unroll
        for(int q=0;q<4;++q) acc[mt][hh*4+q][r] *= inv;
      }
    }
  }

  #pragma unroll
  for(int mt=0; mt<2; ++mt)
    #pragma unroll
    for(int nt=0; nt<8; ++nt)
      #pragma unroll
      for(int r=0; r<4; ++r)
        P[w][mt*16 + g*4 + r][nt*16 + col] = f2bf(acc[mt][nt][r]);

  #pragma unroll
  for(int hh=0; hh<2; ++hh){
    const int head = w*2 + hh;
    const unsigned short* cb = ctxT + ((size_t)(bc*8 + head)) * 4096;
    f32x4 y[4][2] = {};
    #pragma unroll
    for(int ks2=0; ks2<2; ++ks2){
      const bf16x8 pb0 = *(const bf16x8*)(&P[w][col     ][hh*64 + ks2*32 + g*8]);
      const bf16x8 pb1 = *(const bf16x8*)(&P[w][col + 16][hh*64 + ks2*32 + g*8]);
      #pragma unroll
      for(int vt=0; vt<4; ++vt){
        const bf16x8 af = *(const bf16x8*)(cb + (size_t)(vt*16 + col) * 64 + ks2*32 + g*8);
        y[vt][0] = __builtin_amdgcn_mfma_f32_16x16x32_bf16(af, pb0, y[vt][0], 0, 0, 0);
        y[vt][1] = __builtin_amdgcn_mfma_f32_16x16x32_bf16(af, pb1, y[vt][1], 0, 0, 0);
      }
    }
    #pragma unroll
    for(int vt=0; vt<4; ++vt)
      #pragma unroll
      for(int tt=0; tt<2; ++tt)
        #pragma unroll
        for(int r=0; r<4; ++r){
          const size_t a = (size_t)(head*64 + vt*16 + g*4 + r) * 4096 + (size_t)(t0 + tt*16 + col);
          ob[a] = xb[a] + y[vt][tt][r];
        }
  }
}

// ---------------------------------------------------------------------------
extern "C" void kernel_launch(void* const* d_in, const int* in_sizes, int n_in,
                              void* d_out, int out_size, void* d_ws, size_t ws_size,
                              hipStream_t stream)
{
  const float* input = (const float*)d_in[0];
  const float* cond  = (const float*)d_in[1];
  const int*   idx   = (const int*)d_in[2];
  const float* ln_g  = (const float*)d_in[3];
  const float* ln_b  = (const float*)d_in[4];
  const float* tln_g = (const float*)d_in[5];
  const float* tln_b = (const float*)d_in[6];
  const float* Wq    = (const float*)d_in[7];
  const float* bq    = (const float*)d_in[8];
  const float* Wk    = (const float*)d_in[9];
  const float* bk    = (const float*)d_in[10];
  const float* Wv    = (const float*)d_in[11];
  const float* bv    = (const float*)d_in[12];
  float* out = (float*)d_out;
  char*  ws  = (char*)d_ws;

  // workspace layout
  unsigned short* WqT  = (unsigned short*)(ws);                 // 512 KB
  unsigned short* ctxT = (unsigned short*)(ws + 524288);        // 1.5 MB
  float* kbuf = (float*)(ws + 2097152);                         // 3.61 MB
  float* vbuf = (float*)(ws + 2097152 + 3784704);               // 3.61 MB
  unsigned short* xT = (unsigned short*)(ws + 2097152 + 2*3784704); // 96 MB
  const size_t need = 2097152 + 2*(size_t)3784704 + (size_t)24*4096*512*2;

  k_wqt   <<<dim3(1024),    dim3(256), 0, stream>>>(Wq, WqT);
  k_condkv<<<dim3(4,5,24),  dim3(256), 0, stream>>>(cond, idx, tln_g, tln_b, Wk, bk, Wv, bv, kbuf, vbuf);
  k_ctx   <<<dim3(8,24),    dim3(256), 0, stream>>>(kbuf, vbuf, ctxT);
  k_copy  <<<dim3(128,32),  dim3(256), 0, stream>>>(input, idx, out);

  if(ws_size >= need){
    k_lnt <<<dim3(128,24),  dim3(256), 0, stream>>>(input, idx, ln_g, ln_b, xT);
    k_gemm<<<dim3(768,4),   dim3(256), 0, stream>>>(input, idx, xT, WqT, bq, ctxT, out);
  } else {
    k_main<<<dim3(128,24),  dim3(256), 0, stream>>>(input, idx, ln_g, ln_b, WqT, bq, ctxT, out);
  }
}